// Round 4
// baseline (337.868 us; speedup 1.0000x reference)
//
#include <hip/hip_runtime.h>
#include <hip/hip_bf16.h>

typedef __bf16 bf16x8 __attribute__((ext_vector_type(8)));
typedef unsigned short u16x8 __attribute__((ext_vector_type(8)));
typedef float f32x4 __attribute__((ext_vector_type(4)));
typedef __hip_bfloat16 bf16;

// async 16B global -> LDS (lds dest = wave-uniform base + lane*16)
#define GLOAD_LDS16(g, l)                                               \
  __builtin_amdgcn_global_load_lds(                                     \
      (__attribute__((address_space(1))) void*)(void*)(g),              \
      (__attribute__((address_space(3))) void*)(void*)(l), 16, 0, 0)

// ---------------------------------------------------------------------------
// all five fp32 -> bf16 converts in one kernel
// ---------------------------------------------------------------------------
__global__ __launch_bounds__(256) void cvt_all(
    const float4* __restrict__ x,  const float4* __restrict__ qw,
    const float4* __restrict__ kw, const float4* __restrict__ vw,
    const float4* __restrict__ ow,
    ushort4* __restrict__ xb,  ushort4* __restrict__ qwb,
    ushort4* __restrict__ kwb, ushort4* __restrict__ vwb,
    ushort4* __restrict__ owb)
{
  const int i = blockIdx.x * 256 + threadIdx.x;
  const float4* s; ushort4* d; int off;
  if      (i < 2097152) { s = x;  d = xb;  off = i; }
  else if (i < 3145728) { s = qw; d = qwb; off = i - 2097152; }
  else if (i < 3407872) { s = kw; d = kwb; off = i - 3145728; }
  else if (i < 3670016) { s = vw; d = vwb; off = i - 3407872; }
  else                  { s = ow; d = owb; off = i - 3670016; }
  float4 v = s[off];
  bf16 b0 = __float2bfloat16(v.x), b1 = __float2bfloat16(v.y);
  bf16 b2 = __float2bfloat16(v.z), b3 = __float2bfloat16(v.w);
  ushort4 o;
  o.x = *(unsigned short*)&b0; o.y = *(unsigned short*)&b1;
  o.z = *(unsigned short*)&b2; o.w = *(unsigned short*)&b3;
  d[off] = o;
}

// ---------------------------------------------------------------------------
// 256x256 8-phase GEMM (T2+T3+T4+T5): C[M,N] = A[M,K] * W[N,K]^T
// LD = row stride of A/W; KLEN = K-extent this block accumulates (from kbase).
// ATOMIC: epilogue does f32 atomicAdd (for split-K; C must be pre-zeroed).
// Schedule (verified R1): per K-tile 4 phases {ds_read subtile | stage 1
// half-tile | barrier | lgkmcnt(0) | setprio(1) 16xMFMA setprio(0) | barrier};
// counted vmcnt(4) once per tile, never 0 in steady state.
// ---------------------------------------------------------------------------
__device__ __forceinline__ void store_out(bf16* p, float v)  { *p = __float2bfloat16(v); }
__device__ __forceinline__ void store_out(float* p, float v) { *p = v; }

template <typename OutT, int LD, int KLEN, bool ATOMIC>
__device__ __forceinline__ void gemm256_body(
    const bf16* __restrict__ Ag, const bf16* __restrict__ Wg, OutT* __restrict__ C,
    int bm, int bn, int kbase, int N, bf16* As0, bf16* As1, bf16* Bs0, bf16* Bs1)
{
  constexpr int NT = KLEN / 64;
  const int tid   = threadIdx.x;
  const int lane  = tid & 63;
  const int w     = tid >> 6;
  const int wr    = w >> 2;            // 0..1 : A row-half
  const int wc    = w & 3;             // 0..3 : 64-col slice
  const int mfrag = lane & 15;
  const int quad  = lane >> 4;
  const int m7x16 = (mfrag & 7) << 4;  // read-side swizzle XOR

  auto stage_half = [&](const bf16* __restrict__ G, int grow0, int k0, bf16* dsthalf) {
#pragma unroll
    for (int l = 0; l < 2; ++l) {
      const int o    = l * 8192 + tid * 16;       // linear byte off in half
      const int row  = o >> 7;                    // 128 B rows
      const int slot = ((o >> 4) & 7) ^ (row & 7);
      const bf16* src = G + (size_t)(grow0 + row) * LD + kbase + k0 + slot * 8;
      GLOAD_LDS16(src, (char*)dsthalf + l * 8192 + w * 1024);
    }
  };

  stage_half(Ag, bm,       0, As0);
  stage_half(Ag, bm + 128, 0, As0 + 8192);
  stage_half(Wg, bn,       0, Bs0);
  stage_half(Wg, bn + 128, 0, Bs0 + 8192);
  if (NT > 1) {
    stage_half(Wg, bn,       64, Bs1);
    stage_half(Wg, bn + 128, 64, Bs1 + 8192);
    asm volatile("s_waitcnt vmcnt(4)" ::: "memory");
  } else {
    asm volatile("s_waitcnt vmcnt(0)" ::: "memory");
  }
  __builtin_amdgcn_s_barrier();

  f32x4 acc[8][4] = {};

  for (int t = 0; t < NT; ++t) {
    const char* Ab = (const char*)((t & 1) ? As1 : As0);
    const char* Bb = (const char*)((t & 1) ? Bs1 : Bs0);
    bf16* Asn  = (t & 1) ? As0 : As1;  // A dest for tile t+1 (other buffer)
    bf16* Bsn2 = (t & 1) ? Bs1 : Bs0;  // B dest for tile t+2 (same parity as t)

    bf16x8 bfr[4][2];
#pragma unroll
    for (int ph = 0; ph < 4; ++ph) {
      if (ph == 0) {
#pragma unroll
        for (int j = 0; j < 4; ++j) {
          const int rn = wc * 64 + j * 16 + mfrag;
#pragma unroll
          for (int kh = 0; kh < 2; ++kh)
            bfr[j][kh] = *(const bf16x8*)(Bb + ((rn * 128 + kh * 64 + quad * 16) ^ m7x16));
        }
      }
      bf16x8 afr[2][2];
#pragma unroll
      for (int r = 0; r < 2; ++r) {
        const int ra = wr * 128 + (ph * 2 + r) * 16 + mfrag;
#pragma unroll
        for (int kh = 0; kh < 2; ++kh)
          afr[r][kh] = *(const bf16x8*)(Ab + ((ra * 128 + kh * 64 + quad * 16) ^ m7x16));
      }

      if (ph == 0 && t + 1 < NT) stage_half(Ag, bm,       (t + 1) * 64, Asn);
      if (ph == 1 && t + 1 < NT) stage_half(Ag, bm + 128, (t + 1) * 64, Asn + 8192);
      if (ph == 2 && t + 2 < NT) stage_half(Wg, bn,       (t + 2) * 64, Bsn2);
      if (ph == 3 && t + 2 < NT) stage_half(Wg, bn + 128, (t + 2) * 64, Bsn2 + 8192);

      __builtin_amdgcn_s_barrier();
      asm volatile("s_waitcnt lgkmcnt(0)" ::: "memory");
      __builtin_amdgcn_s_setprio(1);
#pragma unroll
      for (int r = 0; r < 2; ++r)
#pragma unroll
        for (int j = 0; j < 4; ++j)
#pragma unroll
          for (int kh = 0; kh < 2; ++kh)
            acc[ph * 2 + r][j] = __builtin_amdgcn_mfma_f32_16x16x32_bf16(
                afr[r][kh], bfr[j][kh], acc[ph * 2 + r][j], 0, 0, 0);
      __builtin_amdgcn_s_setprio(0);
      if (ph == 3) {
        if (t < NT - 2) asm volatile("s_waitcnt vmcnt(4)" ::: "memory");
        else            asm volatile("s_waitcnt vmcnt(0)" ::: "memory");
      }
      __builtin_amdgcn_s_barrier();
    }
  }

  const int rq = quad * 4;
#pragma unroll
  for (int i = 0; i < 8; ++i)
#pragma unroll
    for (int j = 0; j < 4; ++j)
#pragma unroll
      for (int r = 0; r < 4; ++r) {
        const int row = bm + wr * 128 + i * 16 + rq + r;
        const int col = bn + wc * 64 + j * 16 + mfrag;
        if constexpr (ATOMIC)
          atomicAdd((float*)&C[(size_t)row * N + col], acc[i][j][r]);
        else
          store_out(&C[(size_t)row * N + col], acc[i][j][r]);
      }
}

__global__ __launch_bounds__(512, 2) void gemm_qkv256(
    const bf16* __restrict__ X,  const bf16* __restrict__ Wq,
    const bf16* __restrict__ Wk, const bf16* __restrict__ Wv,
    bf16* __restrict__ Qo, bf16* __restrict__ Ko, bf16* __restrict__ Vo)
{
  __shared__ alignas(16) bf16 As[2][16384];
  __shared__ alignas(16) bf16 Bs[2][16384];
  const int bx = blockIdx.x;
  const bf16* W; bf16* C; int N, bn;
  if (bx < 8)       { W = Wq; C = Qo; N = 2048; bn = bx * 256; }
  else if (bx < 10) { W = Wk; C = Ko; N = 512;  bn = (bx - 8) * 256; }
  else              { W = Wv; C = Vo; N = 512;  bn = (bx - 10) * 256; }
  gemm256_body<bf16, 2048, 2048, false>(X, W, C, blockIdx.y * 256, bn, 0, N,
                                        As[0], As[1], Bs[0], Bs[1]);
}

// split-K (2-way): blockIdx.z = K-half; f32 atomicAdd into pre-zeroed out.
// Exactly 2 commutative f32 adds per element -> bit-identical to single-pass.
__global__ __launch_bounds__(512, 2) void gemm_out256(
    const bf16* __restrict__ A, const bf16* __restrict__ W, float* __restrict__ C)
{
  __shared__ alignas(16) bf16 As[2][16384];
  __shared__ alignas(16) bf16 Bs[2][16384];
  gemm256_body<float, 2048, 1024, true>(A, W, C, blockIdx.y * 256,
                                        blockIdx.x * 256, blockIdx.z * 1024,
                                        2048, As[0], As[1], Bs[0], Bs[1]);
}

// ---------------------------------------------------------------------------
// post-QKV fixups in one kernel: rope(Q), rope(K), transpose(V)
// ---------------------------------------------------------------------------
__device__ __forceinline__ void rope_row(
    bf16* __restrict__ buf, const float* __restrict__ gain,
    int nh, float scale, int row)
{
  const int j = threadIdx.x & 63;
  const int bt = row / nh;
  const int h  = row - bt * nh;
  const int t  = bt & 2047;  // T = 2048
  bf16* p = buf + (size_t)bt * (nh * 128) + h * 128;

  float x1 = __bfloat162float(p[j]);
  float x2 = __bfloat162float(p[j + 64]);
  float ss = x1 * x1 + x2 * x2;
#pragma unroll
  for (int off = 32; off > 0; off >>= 1) ss += __shfl_xor(ss, off, 64);
  const float rinv = rsqrtf(ss * (1.0f / 128.0f) + 1.1920928955078125e-07f);
  const float g = gain ? gain[h] : 1.0f;
  const float s = rinv * g * scale;

  // base = 10000 * 2^(128/126) (T=2048 > TRAIN=1024); log2(base) = 14.3035853954
  const float inv_freq = exp2f(-(float)j * (14.3035853954f / 64.0f));
  const float fr = (float)t * inv_freq;
  const float cs = cosf(fr), sn = sinf(fr);
  p[j]      = __float2bfloat16(s * (x1 * cs + x2 * sn));
  p[j + 64] = __float2bfloat16(s * (x2 * cs - x1 * sn));
}

__global__ __launch_bounds__(256) void postqkv(
    bf16* __restrict__ qb, bf16* __restrict__ kb,
    const unsigned short* __restrict__ vb, unsigned short* __restrict__ vtb,
    const float* __restrict__ gain)
{
  const int bx = blockIdx.x;
  if (bx < 16384) {
    rope_row(qb, gain, 16, 0.08838834764831845f, bx * 4 + (threadIdx.x >> 6));
  } else if (bx < 20480) {
    rope_row(kb, nullptr, 4, 1.0f, (bx - 16384) * 4 + (threadIdx.x >> 6));
  } else {
    const int idx = (bx - 20480) * 256 + threadIdx.x;  // 256K threads
    const int t  = idx & 4095;
    const int dc = idx >> 12;                          // [0,64)
    u16x8 v = *(const u16x8*)(vb + (size_t)t * 512 + dc * 8);
#pragma unroll
    for (int j = 0; j < 8; ++j)
      vtb[(size_t)(dc * 8 + j) * 4096 + t] = v[j];
  }
}

// ---------------------------------------------------------------------------
// MFMA flash attention v3 (R1-proven) + T5 setprio around MFMA clusters.
// Causal, GQA (kv head = h>>2). Fixed softmax max M=14 (Cauchy-Schwarz:
// S <= 128*gain/sqrt(128*128) = 11.31 after rmsnorm, so exp(S-14) never
// overflows and needs no online max/rescale). Per-lane l accumulates across
// all tiles; one cross-lane reduction at the end. K and V double-buffered +
// prefetched 1 tile ahead via global_load_lds; ONE barrier per 64-key tile.
// Block = 4 waves = 64 q-rows; q-tile pair (31-p, p) -> uniform 33 tiles.
// LDS 72 KB -> 2 blocks/CU (setprio arbitrates between the 2 blocks: m191).
// ---------------------------------------------------------------------------
__global__ __launch_bounds__(256) void flash_attn(
    const bf16* __restrict__ Q, const bf16* __restrict__ Kg,
    const bf16* __restrict__ Vtg, bf16* __restrict__ Y)
{
  __shared__ bf16 Ks[2][64 * 128];  // [key][d], XOR-swizzled 16B chunks, 2x16 KB
  __shared__ bf16 Vs[2][128 * 64];  // [d][key], swizzled, 2x16 KB
  __shared__ bf16 Ps[4][16 * 64];   // per-wave P [q][key], swizzled, 8 KB

  const int tid = threadIdx.x, lane = tid & 63, w = tid >> 6;
  const int p = blockIdx.x & 15, bh = blockIdx.x >> 4;
  const int h = bh & 15, b = bh >> 4, kvh = h >> 2;
  const int mfrag = lane & 15, quad = lane >> 4;
  const int m7 = mfrag & 7;

  auto stage_k = [&](int kt, int s) {
#pragma unroll
    for (int g = 0; g < 4; ++g) {
      const int o = g * 4096 + w * 1024 + lane * 16;  // byte offset, 256 B rows
      const int r = o >> 8, c = (o >> 4) & 15;
      const int cs = (c & 8) | ((c ^ (r & 7)) & 7);
      const bf16* src = Kg + ((size_t)(b * 2048 + kt * 64 + r)) * 512 + kvh * 128 + cs * 8;
      GLOAD_LDS16(src, (char*)&Ks[s][0] + g * 4096 + w * 1024);
    }
  };
  auto stage_v = [&](int kt, int s) {
#pragma unroll
    for (int g = 0; g < 4; ++g) {
      const int o = g * 4096 + w * 1024 + lane * 16;  // byte offset, 128 B rows
      const int r = o >> 7, c = (o >> 4) & 7;
      const int cs = (c ^ (r & 7)) & 7;
      const bf16* src = Vtg + ((size_t)(kvh * 128 + r)) * 4096 + b * 2048 + kt * 64 + cs * 8;
      GLOAD_LDS16(src, (char*)&Vs[s][0] + g * 4096 + w * 1024);
    }
  };

  stage_k(0, 0);
  stage_v(0, 0);
  int sb = 0;
  bf16* psw = &Ps[w][0];

  for (int phase = 0; phase < 2; ++phase) {
    const int qt = phase ? p : 31 - p;

    bf16x8 qf[4];
    const bf16* qrow = Q + ((size_t)(b * 2048 + qt * 64 + w * 16 + mfrag)) * 2048 + h * 128;
#pragma unroll
    for (int c = 0; c < 4; ++c) qf[c] = *(const bf16x8*)(qrow + c * 32 + quad * 8);

    f32x4 oacc[8] = {};
    float l_lane[4] = {0.f, 0.f, 0.f, 0.f};
    const int q_base = qt * 64 + w * 16 + quad * 4;

    for (int kt = 0; kt <= qt; ++kt) {
      __syncthreads();  // prefetch into [sb] drained; [sb^1] free for overwrite
      const bool last = (phase == 1) && (kt == qt);
      if (!last) {
        const int nk = kt < qt ? kt + 1 : 0;
        stage_k(nk, sb ^ 1);
        stage_v(nk, sb ^ 1);
      }

      // ---- S = Q K^T  (C-layout: row q = quad*4+r, col key = kc*16+mfrag)
      f32x4 sc[4] = {};
      __builtin_amdgcn_s_setprio(1);
#pragma unroll
      for (int kc = 0; kc < 4; ++kc) {
        const bf16* krow = &Ks[sb][0] + (kc * 16 + mfrag) * 128;
#pragma unroll
        for (int c = 0; c < 4; ++c) {
          const int G = 4 * c + quad;
          const int cs = (G & 8) | ((G ^ m7) & 7);
          bf16x8 kf = *(const bf16x8*)(krow + cs * 8);
          sc[kc] = __builtin_amdgcn_mfma_f32_16x16x32_bf16(qf[c], kf, sc[kc], 0, 0, 0);
        }
      }
      __builtin_amdgcn_s_setprio(0);

      // ---- causal mask (diagonal tile only)
      if (kt == qt) {
        const int kcol0 = kt * 64 + mfrag;
#pragma unroll
        for (int kc = 0; kc < 4; ++kc)
#pragma unroll
          for (int r = 0; r < 4; ++r)
            if (kcol0 + kc * 16 > q_base + r) sc[kc][r] = -1e30f;
      }

      // ---- P = exp(S - 14); per-lane l accumulation (no cross-lane ops!)
#pragma unroll
      for (int kc = 0; kc < 4; ++kc)
#pragma unroll
        for (int r = 0; r < 4; ++r) {
          const float pv = __expf(sc[kc][r] - 14.0f);
          l_lane[r] += pv;
          const int q = quad * 4 + r;
          const int slot = ((2 * kc + (mfrag >> 3)) ^ (q & 7)) & 7;
          psw[q * 64 + slot * 8 + m7] = __float2bfloat16(pv);
        }

      // ---- O += P V  (A = own-wave P rows [q][key], B = Vs rows [d][key])
      __builtin_amdgcn_s_setprio(1);
#pragma unroll
      for (int kh = 0; kh < 2; ++kh) {
        const int Gp = 4 * kh + quad;
        const int sl = (Gp ^ m7) & 7;
        bf16x8 pf = *(const bf16x8*)(psw + mfrag * 64 + sl * 8);
#pragma unroll
        for (int dc = 0; dc < 8; ++dc) {
          bf16x8 vf = *(const bf16x8*)(&Vs[sb][0] + (dc * 16 + mfrag) * 64 + sl * 8);
          oacc[dc] = __builtin_amdgcn_mfma_f32_16x16x32_bf16(pf, vf, oacc[dc], 0, 0, 0);
        }
      }
      __builtin_amdgcn_s_setprio(0);
      sb ^= 1;
    }

    // ---- epilogue: reduce l across the 16 lanes holding each row, store
#pragma unroll
    for (int r = 0; r < 4; ++r) {
      float l = l_lane[r];
      l += __shfl_xor(l, 1, 64);
      l += __shfl_xor(l, 2, 64);
      l += __shfl_xor(l, 4, 64);
      l += __shfl_xor(l, 8, 64);
      const float linv = 1.0f / l;
      const size_t row = (size_t)(b * 2048 + q_base + r);
#pragma unroll
      for (int dc = 0; dc < 8; ++dc)
        Y[row * 2048 + h * 128 + dc * 16 + mfrag] = __float2bfloat16(oacc[dc][r] * linv);
    }
  }
}

// ---------------------------------------------------------------------------
extern "C" void kernel_launch(void* const* d_in, const int* in_sizes, int n_in,
                              void* d_out, int out_size, void* d_ws, size_t ws_size,
                              hipStream_t stream)
{
  const float* x      = (const float*)d_in[0];
  const float* q_w    = (const float*)d_in[1];
  const float* k_w    = (const float*)d_in[2];
  const float* v_w    = (const float*)d_in[3];
  const float* o_w    = (const float*)d_in[4];
  const float* q_gain = (const float*)d_in[5];
  float* out = (float*)d_out;

  // workspace (bf16): xb aliases yb (x dead after QKV GEMM); vtb reuses qwb
  // region (q_w copy dead after QKV GEMM).
  char* ws = (char*)d_ws;
  bf16* xb  = (bf16*)(ws);                   // 4096x2048 = 16 MB
  bf16* yb  = (bf16*)(ws);                   // alias of xb
  bf16* qwb = (bf16*)(ws + (16u << 20));     // 2048x2048 = 8 MB
  bf16* vtb = (bf16*)(ws + (16u << 20));     // 512x4096  = 4 MB (after qwb dead)
  bf16* owb = (bf16*)(ws + (24u << 20));     // 2048x2048 = 8 MB
  bf16* kwb = (bf16*)(ws + (32u << 20));     // 512x2048  = 2 MB
  bf16* vwb = (bf16*)(ws + (34u << 20));     // 512x2048  = 2 MB
  bf16* qb  = (bf16*)(ws + (36u << 20));     // 4096x2048 = 16 MB
  bf16* kb  = (bf16*)(ws + (52u << 20));     // 4096x512  = 4 MB
  bf16* vb  = (bf16*)(ws + (56u << 20));     // 4096x512  = 4 MB  (total 60 MB)

  // zero the f32 output for split-K atomic accumulation (graph-safe async op)
  hipMemsetAsync(out, 0, (size_t)4096 * 2048 * sizeof(float), stream);

  cvt_all<<<dim3(18432), dim3(256), 0, stream>>>(
      (const float4*)x, (const float4*)q_w, (const float4*)k_w,
      (const float4*)v_w, (const float4*)o_w,
      (ushort4*)xb, (ushort4*)qwb, (ushort4*)kwb, (ushort4*)vwb, (ushort4*)owb);

  gemm_qkv256<<<dim3(12, 16), dim3(512), 0, stream>>>(xb, qwb, kwb, vwb, qb, kb, vb);

  postqkv<<<dim3(21504), dim3(256), 0, stream>>>(
      qb, kb, (const unsigned short*)vb, (unsigned short*)vtb, q_gain);

  flash_attn<<<dim3(512), dim3(256), 0, stream>>>(qb, kb, vtb, yb);

  gemm_out256<<<dim3(8, 16, 2), dim3(512), 0, stream>>>(yb, owb, out);
}

// Round 5
// 312.774 us; speedup vs baseline: 1.0802x; 1.0802x over previous
//
#include <hip/hip_runtime.h>
#include <hip/hip_bf16.h>

typedef __bf16 bf16x8 __attribute__((ext_vector_type(8)));
typedef unsigned short u16x8 __attribute__((ext_vector_type(8)));
typedef float f32x4 __attribute__((ext_vector_type(4)));
typedef __hip_bfloat16 bf16;

// async 16B global -> LDS (lds dest = wave-uniform base + lane*16)
#define GLOAD_LDS16(g, l)                                               \
  __builtin_amdgcn_global_load_lds(                                     \
      (__attribute__((address_space(1))) void*)(void*)(g),              \
      (__attribute__((address_space(3))) void*)(void*)(l), 16, 0, 0)

// ---------------------------------------------------------------------------
// all five fp32 -> bf16 converts in one kernel
// ---------------------------------------------------------------------------
__global__ __launch_bounds__(256) void cvt_all(
    const float4* __restrict__ x,  const float4* __restrict__ qw,
    const float4* __restrict__ kw, const float4* __restrict__ vw,
    const float4* __restrict__ ow,
    ushort4* __restrict__ xb,  ushort4* __restrict__ qwb,
    ushort4* __restrict__ kwb, ushort4* __restrict__ vwb,
    ushort4* __restrict__ owb)
{
  const int i = blockIdx.x * 256 + threadIdx.x;
  const float4* s; ushort4* d; int off;
  if      (i < 2097152) { s = x;  d = xb;  off = i; }
  else if (i < 3145728) { s = qw; d = qwb; off = i - 2097152; }
  else if (i < 3407872) { s = kw; d = kwb; off = i - 3145728; }
  else if (i < 3670016) { s = vw; d = vwb; off = i - 3407872; }
  else                  { s = ow; d = owb; off = i - 3670016; }
  float4 v = s[off];
  bf16 b0 = __float2bfloat16(v.x), b1 = __float2bfloat16(v.y);
  bf16 b2 = __float2bfloat16(v.z), b3 = __float2bfloat16(v.w);
  ushort4 o;
  o.x = *(unsigned short*)&b0; o.y = *(unsigned short*)&b1;
  o.z = *(unsigned short*)&b2; o.w = *(unsigned short*)&b3;
  d[off] = o;
}

// ---------------------------------------------------------------------------
// 256x256 8-phase GEMM (T2+T3+T4+T5): C[M,N] = A[M,K] * W[N,K]^T
// (verified R1/R4 schedule; per K-tile 4 phases, counted vmcnt(4), never 0
// in steady state; read-side XOR swizzle, linear global_load_lds dest.)
// ---------------------------------------------------------------------------
__device__ __forceinline__ void store_out(bf16* p, float v)  { *p = __float2bfloat16(v); }
__device__ __forceinline__ void store_out(float* p, float v) { *p = v; }

template <typename OutT, int LD, int KLEN>
__device__ __forceinline__ void gemm256_body(
    const bf16* __restrict__ Ag, const bf16* __restrict__ Wg, OutT* __restrict__ C,
    int bm, int bn, int N, bf16* As0, bf16* As1, bf16* Bs0, bf16* Bs1)
{
  constexpr int NT = KLEN / 64;
  const int tid   = threadIdx.x;
  const int lane  = tid & 63;
  const int w     = tid >> 6;
  const int wr    = w >> 2;            // 0..1 : A row-half
  const int wc    = w & 3;             // 0..3 : 64-col slice
  const int mfrag = lane & 15;
  const int quad  = lane >> 4;
  const int m7x16 = (mfrag & 7) << 4;  // read-side swizzle XOR

  auto stage_half = [&](const bf16* __restrict__ G, int grow0, int k0, bf16* dsthalf) {
#pragma unroll
    for (int l = 0; l < 2; ++l) {
      const int o    = l * 8192 + tid * 16;       // linear byte off in half
      const int row  = o >> 7;                    // 128 B rows
      const int slot = ((o >> 4) & 7) ^ (row & 7);
      const bf16* src = G + (size_t)(grow0 + row) * LD + k0 + slot * 8;
      GLOAD_LDS16(src, (char*)dsthalf + l * 8192 + w * 1024);
    }
  };

  stage_half(Ag, bm,       0, As0);
  stage_half(Ag, bm + 128, 0, As0 + 8192);
  stage_half(Wg, bn,       0, Bs0);
  stage_half(Wg, bn + 128, 0, Bs0 + 8192);
  if (NT > 1) {
    stage_half(Wg, bn,       64, Bs1);
    stage_half(Wg, bn + 128, 64, Bs1 + 8192);
    asm volatile("s_waitcnt vmcnt(4)" ::: "memory");
  } else {
    asm volatile("s_waitcnt vmcnt(0)" ::: "memory");
  }
  __builtin_amdgcn_s_barrier();

  f32x4 acc[8][4] = {};

  for (int t = 0; t < NT; ++t) {
    const char* Ab = (const char*)((t & 1) ? As1 : As0);
    const char* Bb = (const char*)((t & 1) ? Bs1 : Bs0);
    bf16* Asn  = (t & 1) ? As0 : As1;  // A dest for tile t+1 (other buffer)
    bf16* Bsn2 = (t & 1) ? Bs1 : Bs0;  // B dest for tile t+2 (same parity as t)

    bf16x8 bfr[4][2];
#pragma unroll
    for (int ph = 0; ph < 4; ++ph) {
      if (ph == 0) {
#pragma unroll
        for (int j = 0; j < 4; ++j) {
          const int rn = wc * 64 + j * 16 + mfrag;
#pragma unroll
          for (int kh = 0; kh < 2; ++kh)
            bfr[j][kh] = *(const bf16x8*)(Bb + ((rn * 128 + kh * 64 + quad * 16) ^ m7x16));
        }
      }
      bf16x8 afr[2][2];
#pragma unroll
      for (int r = 0; r < 2; ++r) {
        const int ra = wr * 128 + (ph * 2 + r) * 16 + mfrag;
#pragma unroll
        for (int kh = 0; kh < 2; ++kh)
          afr[r][kh] = *(const bf16x8*)(Ab + ((ra * 128 + kh * 64 + quad * 16) ^ m7x16));
      }

      if (ph == 0 && t + 1 < NT) stage_half(Ag, bm,       (t + 1) * 64, Asn);
      if (ph == 1 && t + 1 < NT) stage_half(Ag, bm + 128, (t + 1) * 64, Asn + 8192);
      if (ph == 2 && t + 2 < NT) stage_half(Wg, bn,       (t + 2) * 64, Bsn2);
      if (ph == 3 && t + 2 < NT) stage_half(Wg, bn + 128, (t + 2) * 64, Bsn2 + 8192);

      __builtin_amdgcn_s_barrier();
      asm volatile("s_waitcnt lgkmcnt(0)" ::: "memory");
      __builtin_amdgcn_s_setprio(1);
#pragma unroll
      for (int r = 0; r < 2; ++r)
#pragma unroll
        for (int j = 0; j < 4; ++j)
#pragma unroll
          for (int kh = 0; kh < 2; ++kh)
            acc[ph * 2 + r][j] = __builtin_amdgcn_mfma_f32_16x16x32_bf16(
                afr[r][kh], bfr[j][kh], acc[ph * 2 + r][j], 0, 0, 0);
      __builtin_amdgcn_s_setprio(0);
      if (ph == 3) {
        if (t < NT - 2) asm volatile("s_waitcnt vmcnt(4)" ::: "memory");
        else            asm volatile("s_waitcnt vmcnt(0)" ::: "memory");
      }
      __builtin_amdgcn_s_barrier();
    }
  }

  const int rq = quad * 4;
#pragma unroll
  for (int i = 0; i < 8; ++i)
#pragma unroll
    for (int j = 0; j < 4; ++j)
#pragma unroll
      for (int r = 0; r < 4; ++r) {
        const int row = bm + wr * 128 + i * 16 + rq + r;
        const int col = bn + wc * 64 + j * 16 + mfrag;
        store_out(&C[(size_t)row * N + col], acc[i][j][r]);
      }
}

// ---------------------------------------------------------------------------
// 256x128 variant (same verified schedule, narrower B): 3 stage_half per
// tile (A half0, A half1, B). Steady-state drain vmcnt(2): at tile t ph3 the
// queue is [B(t+1), A0(t+1), A1(t+1), B(t+2)] (8 loads); draining 6 oldest
// completes tile t+1's operands and leaves exactly B(t+2) in flight.
// LDS: A 2x32KB + B 2x16KB = 96 KB.
// ---------------------------------------------------------------------------
template <typename OutT, int LD, int KLEN>
__device__ __forceinline__ void gemm256x128_body(
    const bf16* __restrict__ Ag, const bf16* __restrict__ Wg, OutT* __restrict__ C,
    int bm, int bn, int N, bf16* As0, bf16* As1, bf16* Bs0, bf16* Bs1)
{
  constexpr int NT = KLEN / 64;
  const int tid   = threadIdx.x;
  const int lane  = tid & 63;
  const int w     = tid >> 6;
  const int wr    = w >> 2;            // 0..1 : A row-half (128 rows)
  const int wc    = w & 3;             // 0..3 : 32-col slice
  const int mfrag = lane & 15;
  const int quad  = lane >> 4;
  const int m7x16 = (mfrag & 7) << 4;

  auto stage_half = [&](const bf16* __restrict__ G, int grow0, int k0, bf16* dsthalf) {
#pragma unroll
    for (int l = 0; l < 2; ++l) {
      const int o    = l * 8192 + tid * 16;
      const int row  = o >> 7;
      const int slot = ((o >> 4) & 7) ^ (row & 7);
      const bf16* src = G + (size_t)(grow0 + row) * LD + k0 + slot * 8;
      GLOAD_LDS16(src, (char*)dsthalf + l * 8192 + w * 1024);
    }
  };

  // prologue: tile 0 complete + B(1) in flight
  stage_half(Ag, bm,       0, As0);
  stage_half(Ag, bm + 128, 0, As0 + 8192);
  stage_half(Wg, bn, 0, Bs0);
  stage_half(Wg, bn, 64, Bs1);
  asm volatile("s_waitcnt vmcnt(2)" ::: "memory");
  __builtin_amdgcn_s_barrier();

  f32x4 acc[8][2] = {};

  for (int t = 0; t < NT; ++t) {
    const char* Ab = (const char*)((t & 1) ? As1 : As0);
    const char* Bb = (const char*)((t & 1) ? Bs1 : Bs0);
    bf16* Asn  = (t & 1) ? As0 : As1;
    bf16* Bsn2 = (t & 1) ? Bs1 : Bs0;

    bf16x8 bfr[2][2];
#pragma unroll
    for (int ph = 0; ph < 4; ++ph) {
      if (ph == 0) {
#pragma unroll
        for (int j = 0; j < 2; ++j) {
          const int rn = wc * 32 + j * 16 + mfrag;
#pragma unroll
          for (int kh = 0; kh < 2; ++kh)
            bfr[j][kh] = *(const bf16x8*)(Bb + ((rn * 128 + kh * 64 + quad * 16) ^ m7x16));
        }
      }
      bf16x8 afr[2][2];
#pragma unroll
      for (int r = 0; r < 2; ++r) {
        const int ra = wr * 128 + (ph * 2 + r) * 16 + mfrag;
#pragma unroll
        for (int kh = 0; kh < 2; ++kh)
          afr[r][kh] = *(const bf16x8*)(Ab + ((ra * 128 + kh * 64 + quad * 16) ^ m7x16));
      }

      if (ph == 0 && t + 1 < NT) stage_half(Ag, bm,       (t + 1) * 64, Asn);
      if (ph == 1 && t + 1 < NT) stage_half(Ag, bm + 128, (t + 1) * 64, Asn + 8192);
      if (ph == 2 && t + 2 < NT) stage_half(Wg, bn,       (t + 2) * 64, Bsn2);

      __builtin_amdgcn_s_barrier();
      asm volatile("s_waitcnt lgkmcnt(0)" ::: "memory");
      __builtin_amdgcn_s_setprio(1);
#pragma unroll
      for (int r = 0; r < 2; ++r)
#pragma unroll
        for (int j = 0; j < 2; ++j)
#pragma unroll
          for (int kh = 0; kh < 2; ++kh)
            acc[ph * 2 + r][j] = __builtin_amdgcn_mfma_f32_16x16x32_bf16(
                afr[r][kh], bfr[j][kh], acc[ph * 2 + r][j], 0, 0, 0);
      __builtin_amdgcn_s_setprio(0);
      if (ph == 3) {
        if (t < NT - 2) asm volatile("s_waitcnt vmcnt(2)" ::: "memory");
        else            asm volatile("s_waitcnt vmcnt(0)" ::: "memory");
      }
      __builtin_amdgcn_s_barrier();
    }
  }

  const int rq = quad * 4;
#pragma unroll
  for (int i = 0; i < 8; ++i)
#pragma unroll
    for (int j = 0; j < 2; ++j)
#pragma unroll
      for (int r = 0; r < 4; ++r) {
        const int row = bm + wr * 128 + i * 16 + rq + r;
        const int col = bn + wc * 32 + j * 16 + mfrag;
        store_out(&C[(size_t)row * N + col], acc[i][j][r]);
      }
}

// qkv: grid 12x16 = 192 blocks; XCD-chunked swizzle (192 = 8*24, bijective)
__global__ __launch_bounds__(512, 2) void gemm_qkv256(
    const bf16* __restrict__ X,  const bf16* __restrict__ Wq,
    const bf16* __restrict__ Wk, const bf16* __restrict__ Wv,
    bf16* __restrict__ Qo, bf16* __restrict__ Ko, bf16* __restrict__ Vo)
{
  __shared__ alignas(16) bf16 As[2][16384];
  __shared__ alignas(16) bf16 Bs[2][16384];
  const int orig = blockIdx.y * 12 + blockIdx.x;
  const int swz  = (orig & 7) * 24 + (orig >> 3);
  const int bx   = swz % 12;
  const int by   = swz / 12;
  const bf16* W; bf16* C; int N, bn;
  if (bx < 8)       { W = Wq; C = Qo; N = 2048; bn = bx * 256; }
  else if (bx < 10) { W = Wk; C = Ko; N = 512;  bn = (bx - 8) * 256; }
  else              { W = Wv; C = Vo; N = 512;  bn = (bx - 10) * 256; }
  gemm256_body<bf16, 2048, 2048>(X, W, C, by * 256, bn, N,
                                 As[0], As[1], Bs[0], Bs[1]);
}

// out-proj: BM=256 x BN=128 -> grid 16x16 = 256 blocks (full machine, no
// split-K, no atomics); XCD-chunked swizzle (256 = 8*32, bijective)
__global__ __launch_bounds__(512, 2) void gemm_out256(
    const bf16* __restrict__ A, const bf16* __restrict__ W, float* __restrict__ C)
{
  __shared__ alignas(16) bf16 As[2][16384];
  __shared__ alignas(16) bf16 Bs[2][8192];
  const int orig = blockIdx.y * 16 + blockIdx.x;
  const int swz  = (orig & 7) * 32 + (orig >> 3);
  const int bx   = swz & 15;
  const int by   = swz >> 4;
  gemm256x128_body<float, 2048, 2048>(A, W, C, by * 256, bx * 128, 2048,
                                      As[0], As[1], Bs[0], Bs[1]);
}

// ---------------------------------------------------------------------------
// post-QKV fixups in one kernel: rope(Q), rope(K), transpose(V)
// ---------------------------------------------------------------------------
__device__ __forceinline__ void rope_row(
    bf16* __restrict__ buf, const float* __restrict__ gain,
    int nh, float scale, int row)
{
  const int j = threadIdx.x & 63;
  const int bt = row / nh;
  const int h  = row - bt * nh;
  const int t  = bt & 2047;  // T = 2048
  bf16* p = buf + (size_t)bt * (nh * 128) + h * 128;

  float x1 = __bfloat162float(p[j]);
  float x2 = __bfloat162float(p[j + 64]);
  float ss = x1 * x1 + x2 * x2;
#pragma unroll
  for (int off = 32; off > 0; off >>= 1) ss += __shfl_xor(ss, off, 64);
  const float rinv = rsqrtf(ss * (1.0f / 128.0f) + 1.1920928955078125e-07f);
  const float g = gain ? gain[h] : 1.0f;
  const float s = rinv * g * scale;

  // base = 10000 * 2^(128/126) (T=2048 > TRAIN=1024); log2(base) = 14.3035853954
  const float inv_freq = exp2f(-(float)j * (14.3035853954f / 64.0f));
  const float fr = (float)t * inv_freq;
  const float cs = cosf(fr), sn = sinf(fr);
  p[j]      = __float2bfloat16(s * (x1 * cs + x2 * sn));
  p[j + 64] = __float2bfloat16(s * (x2 * cs - x1 * sn));
}

__global__ __launch_bounds__(256) void postqkv(
    bf16* __restrict__ qb, bf16* __restrict__ kb,
    const unsigned short* __restrict__ vb, unsigned short* __restrict__ vtb,
    const float* __restrict__ gain)
{
  const int bx = blockIdx.x;
  if (bx < 16384) {
    rope_row(qb, gain, 16, 0.08838834764831845f, bx * 4 + (threadIdx.x >> 6));
  } else if (bx < 20480) {
    rope_row(kb, nullptr, 4, 1.0f, (bx - 16384) * 4 + (threadIdx.x >> 6));
  } else {
    const int idx = (bx - 20480) * 256 + threadIdx.x;  // 256K threads
    const int t  = idx & 4095;
    const int dc = idx >> 12;                          // [0,64)
    u16x8 v = *(const u16x8*)(vb + (size_t)t * 512 + dc * 8);
#pragma unroll
    for (int j = 0; j < 8; ++j)
      vtb[(size_t)(dc * 8 + j) * 4096 + t] = v[j];
  }
}

// ---------------------------------------------------------------------------
// MFMA flash attention v3 (R1-proven) + T5 setprio around MFMA clusters.
// Causal, GQA (kv head = h>>2). Fixed softmax max M=14 (Cauchy-Schwarz:
// S <= 128*gain/sqrt(128*128) = 11.31 after rmsnorm, so exp(S-14) never
// overflows and needs no online max/rescale). Per-lane l accumulates across
// all tiles; one cross-lane reduction at the end. K and V double-buffered +
// prefetched 1 tile ahead via global_load_lds; ONE barrier per 64-key tile.
// Block = 4 waves = 64 q-rows; q-tile pair (31-p, p) -> uniform 33 tiles.
// LDS 72 KB -> 2 blocks/CU (setprio arbitrates between the 2 blocks: m191).
// ---------------------------------------------------------------------------
__global__ __launch_bounds__(256) void flash_attn(
    const bf16* __restrict__ Q, const bf16* __restrict__ Kg,
    const bf16* __restrict__ Vtg, bf16* __restrict__ Y)
{
  __shared__ bf16 Ks[2][64 * 128];  // [key][d], XOR-swizzled 16B chunks, 2x16 KB
  __shared__ bf16 Vs[2][128 * 64];  // [d][key], swizzled, 2x16 KB
  __shared__ bf16 Ps[4][16 * 64];   // per-wave P [q][key], swizzled, 8 KB

  const int tid = threadIdx.x, lane = tid & 63, w = tid >> 6;
  const int p = blockIdx.x & 15, bh = blockIdx.x >> 4;
  const int h = bh & 15, b = bh >> 4, kvh = h >> 2;
  const int mfrag = lane & 15, quad = lane >> 4;
  const int m7 = mfrag & 7;

  auto stage_k = [&](int kt, int s) {
#pragma unroll
    for (int g = 0; g < 4; ++g) {
      const int o = g * 4096 + w * 1024 + lane * 16;  // byte offset, 256 B rows
      const int r = o >> 8, c = (o >> 4) & 15;
      const int cs = (c & 8) | ((c ^ (r & 7)) & 7);
      const bf16* src = Kg + ((size_t)(b * 2048 + kt * 64 + r)) * 512 + kvh * 128 + cs * 8;
      GLOAD_LDS16(src, (char*)&Ks[s][0] + g * 4096 + w * 1024);
    }
  };
  auto stage_v = [&](int kt, int s) {
#pragma unroll
    for (int g = 0; g < 4; ++g) {
      const int o = g * 4096 + w * 1024 + lane * 16;  // byte offset, 128 B rows
      const int r = o >> 7, c = (o >> 4) & 7;
      const int cs = (c ^ (r & 7)) & 7;
      const bf16* src = Vtg + ((size_t)(kvh * 128 + r)) * 4096 + b * 2048 + kt * 64 + cs * 8;
      GLOAD_LDS16(src, (char*)&Vs[s][0] + g * 4096 + w * 1024);
    }
  };

  stage_k(0, 0);
  stage_v(0, 0);
  int sb = 0;
  bf16* psw = &Ps[w][0];

  for (int phase = 0; phase < 2; ++phase) {
    const int qt = phase ? p : 31 - p;

    bf16x8 qf[4];
    const bf16* qrow = Q + ((size_t)(b * 2048 + qt * 64 + w * 16 + mfrag)) * 2048 + h * 128;
#pragma unroll
    for (int c = 0; c < 4; ++c) qf[c] = *(const bf16x8*)(qrow + c * 32 + quad * 8);

    f32x4 oacc[8] = {};
    float l_lane[4] = {0.f, 0.f, 0.f, 0.f};
    const int q_base = qt * 64 + w * 16 + quad * 4;

    for (int kt = 0; kt <= qt; ++kt) {
      __syncthreads();  // prefetch into [sb] drained; [sb^1] free for overwrite
      const bool last = (phase == 1) && (kt == qt);
      if (!last) {
        const int nk = kt < qt ? kt + 1 : 0;
        stage_k(nk, sb ^ 1);
        stage_v(nk, sb ^ 1);
      }

      // ---- S = Q K^T  (C-layout: row q = quad*4+r, col key = kc*16+mfrag)
      f32x4 sc[4] = {};
      __builtin_amdgcn_s_setprio(1);
#pragma unroll
      for (int kc = 0; kc < 4; ++kc) {
        const bf16* krow = &Ks[sb][0] + (kc * 16 + mfrag) * 128;
#pragma unroll
        for (int c = 0; c < 4; ++c) {
          const int G = 4 * c + quad;
          const int cs = (G & 8) | ((G ^ m7) & 7);
          bf16x8 kf = *(const bf16x8*)(krow + cs * 8);
          sc[kc] = __builtin_amdgcn_mfma_f32_16x16x32_bf16(qf[c], kf, sc[kc], 0, 0, 0);
        }
      }
      __builtin_amdgcn_s_setprio(0);

      // ---- causal mask (diagonal tile only)
      if (kt == qt) {
        const int kcol0 = kt * 64 + mfrag;
#pragma unroll
        for (int kc = 0; kc < 4; ++kc)
#pragma unroll
          for (int r = 0; r < 4; ++r)
            if (kcol0 + kc * 16 > q_base + r) sc[kc][r] = -1e30f;
      }

      // ---- P = exp(S - 14); per-lane l accumulation (no cross-lane ops!)
#pragma unroll
      for (int kc = 0; kc < 4; ++kc)
#pragma unroll
        for (int r = 0; r < 4; ++r) {
          const float pv = __expf(sc[kc][r] - 14.0f);
          l_lane[r] += pv;
          const int q = quad * 4 + r;
          const int slot = ((2 * kc + (mfrag >> 3)) ^ (q & 7)) & 7;
          psw[q * 64 + slot * 8 + m7] = __float2bfloat16(pv);
        }

      // ---- O += P V  (A = own-wave P rows [q][key], B = Vs rows [d][key])
      __builtin_amdgcn_s_setprio(1);
#pragma unroll
      for (int kh = 0; kh < 2; ++kh) {
        const int Gp = 4 * kh + quad;
        const int sl = (Gp ^ m7) & 7;
        bf16x8 pf = *(const bf16x8*)(psw + mfrag * 64 + sl * 8);
#pragma unroll
        for (int dc = 0; dc < 8; ++dc) {
          bf16x8 vf = *(const bf16x8*)(&Vs[sb][0] + (dc * 16 + mfrag) * 64 + sl * 8);
          oacc[dc] = __builtin_amdgcn_mfma_f32_16x16x32_bf16(pf, vf, oacc[dc], 0, 0, 0);
        }
      }
      __builtin_amdgcn_s_setprio(0);
      sb ^= 1;
    }

    // ---- epilogue: reduce l across the 16 lanes holding each row, store
#pragma unroll
    for (int r = 0; r < 4; ++r) {
      float l = l_lane[r];
      l += __shfl_xor(l, 1, 64);
      l += __shfl_xor(l, 2, 64);
      l += __shfl_xor(l, 4, 64);
      l += __shfl_xor(l, 8, 64);
      const float linv = 1.0f / l;
      const size_t row = (size_t)(b * 2048 + q_base + r);
#pragma unroll
      for (int dc = 0; dc < 8; ++dc)
        Y[row * 2048 + h * 128 + dc * 16 + mfrag] = __float2bfloat16(oacc[dc][r] * linv);
    }
  }
}

// ---------------------------------------------------------------------------
extern "C" void kernel_launch(void* const* d_in, const int* in_sizes, int n_in,
                              void* d_out, int out_size, void* d_ws, size_t ws_size,
                              hipStream_t stream)
{
  const float* x      = (const float*)d_in[0];
  const float* q_w    = (const float*)d_in[1];
  const float* k_w    = (const float*)d_in[2];
  const float* v_w    = (const float*)d_in[3];
  const float* o_w    = (const float*)d_in[4];
  const float* q_gain = (const float*)d_in[5];
  float* out = (float*)d_out;

  // workspace (bf16): xb aliases yb (x dead after QKV GEMM); vtb reuses qwb
  // region (q_w copy dead after QKV GEMM).
  char* ws = (char*)d_ws;
  bf16* xb  = (bf16*)(ws);                   // 4096x2048 = 16 MB
  bf16* yb  = (bf16*)(ws);                   // alias of xb
  bf16* qwb = (bf16*)(ws + (16u << 20));     // 2048x2048 = 8 MB
  bf16* vtb = (bf16*)(ws + (16u << 20));     // 512x4096  = 4 MB (after qwb dead)
  bf16* owb = (bf16*)(ws + (24u << 20));     // 2048x2048 = 8 MB
  bf16* kwb = (bf16*)(ws + (32u << 20));     // 512x2048  = 2 MB
  bf16* vwb = (bf16*)(ws + (34u << 20));     // 512x2048  = 2 MB
  bf16* qb  = (bf16*)(ws + (36u << 20));     // 4096x2048 = 16 MB
  bf16* kb  = (bf16*)(ws + (52u << 20));     // 4096x512  = 4 MB
  bf16* vb  = (bf16*)(ws + (56u << 20));     // 4096x512  = 4 MB  (total 60 MB)

  cvt_all<<<dim3(18432), dim3(256), 0, stream>>>(
      (const float4*)x, (const float4*)q_w, (const float4*)k_w,
      (const float4*)v_w, (const float4*)o_w,
      (ushort4*)xb, (ushort4*)qwb, (ushort4*)kwb, (ushort4*)vwb, (ushort4*)owb);

  gemm_qkv256<<<dim3(12, 16), dim3(512), 0, stream>>>(xb, qwb, kwb, vwb, qb, kb, vb);

  postqkv<<<dim3(21504), dim3(256), 0, stream>>>(
      qb, kb, (const unsigned short*)vb, (unsigned short*)vtb, q_gain);

  flash_attn<<<dim3(512), dim3(256), 0, stream>>>(qb, kb, vtb, yb);

  gemm_out256<<<dim3(16, 16), dim3(512), 0, stream>>>(yb, owb, out);
}

// Round 6
// 305.096 us; speedup vs baseline: 1.1074x; 1.0252x over previous
//
#include <hip/hip_runtime.h>
#include <hip/hip_bf16.h>

typedef __bf16 bf16x8 __attribute__((ext_vector_type(8)));
typedef unsigned short u16x8 __attribute__((ext_vector_type(8)));
typedef float f32x4 __attribute__((ext_vector_type(4)));
typedef __hip_bfloat16 bf16;

// async 16B global -> LDS (lds dest = wave-uniform base + lane*16)
#define GLOAD_LDS16(g, l)                                               \
  __builtin_amdgcn_global_load_lds(                                     \
      (__attribute__((address_space(1))) void*)(void*)(g),              \
      (__attribute__((address_space(3))) void*)(void*)(l), 16, 0, 0)

// ---------------------------------------------------------------------------
// all five fp32 -> bf16 converts in one kernel
// ---------------------------------------------------------------------------
__global__ __launch_bounds__(256) void cvt_all(
    const float4* __restrict__ x,  const float4* __restrict__ qw,
    const float4* __restrict__ kw, const float4* __restrict__ vw,
    const float4* __restrict__ ow,
    ushort4* __restrict__ xb,  ushort4* __restrict__ qwb,
    ushort4* __restrict__ kwb, ushort4* __restrict__ vwb,
    ushort4* __restrict__ owb)
{
  const int i = blockIdx.x * 256 + threadIdx.x;
  const float4* s; ushort4* d; int off;
  if      (i < 2097152) { s = x;  d = xb;  off = i; }
  else if (i < 3145728) { s = qw; d = qwb; off = i - 2097152; }
  else if (i < 3407872) { s = kw; d = kwb; off = i - 3145728; }
  else if (i < 3670016) { s = vw; d = vwb; off = i - 3407872; }
  else                  { s = ow; d = owb; off = i - 3670016; }
  float4 v = s[off];
  bf16 b0 = __float2bfloat16(v.x), b1 = __float2bfloat16(v.y);
  bf16 b2 = __float2bfloat16(v.z), b3 = __float2bfloat16(v.w);
  ushort4 o;
  o.x = *(unsigned short*)&b0; o.y = *(unsigned short*)&b1;
  o.z = *(unsigned short*)&b2; o.w = *(unsigned short*)&b3;
  d[off] = o;
}

// ---------------------------------------------------------------------------
// 256x256 8-phase GEMM (T2+T3+T4+T5): C[M,N] = A[M,K] * W[N,K]^T
// (verified R1/R4/R5 schedule; per K-tile 4 phases, counted vmcnt(4), never 0
// in steady state; read-side XOR swizzle, linear global_load_lds dest.)
// ---------------------------------------------------------------------------
__device__ __forceinline__ void store_out(bf16* p, float v)  { *p = __float2bfloat16(v); }
__device__ __forceinline__ void store_out(float* p, float v) { *p = v; }

template <typename OutT, int LD, int KLEN>
__device__ __forceinline__ void gemm256_body(
    const bf16* __restrict__ Ag, const bf16* __restrict__ Wg, OutT* __restrict__ C,
    int bm, int bn, int N, bf16* As0, bf16* As1, bf16* Bs0, bf16* Bs1)
{
  constexpr int NT = KLEN / 64;
  const int tid   = threadIdx.x;
  const int lane  = tid & 63;
  const int w     = tid >> 6;
  const int wr    = w >> 2;            // 0..1 : A row-half
  const int wc    = w & 3;             // 0..3 : 64-col slice
  const int mfrag = lane & 15;
  const int quad  = lane >> 4;
  const int m7x16 = (mfrag & 7) << 4;  // read-side swizzle XOR

  auto stage_half = [&](const bf16* __restrict__ G, int grow0, int k0, bf16* dsthalf) {
#pragma unroll
    for (int l = 0; l < 2; ++l) {
      const int o    = l * 8192 + tid * 16;       // linear byte off in half
      const int row  = o >> 7;                    // 128 B rows
      const int slot = ((o >> 4) & 7) ^ (row & 7);
      const bf16* src = G + (size_t)(grow0 + row) * LD + k0 + slot * 8;
      GLOAD_LDS16(src, (char*)dsthalf + l * 8192 + w * 1024);
    }
  };

  stage_half(Ag, bm,       0, As0);
  stage_half(Ag, bm + 128, 0, As0 + 8192);
  stage_half(Wg, bn,       0, Bs0);
  stage_half(Wg, bn + 128, 0, Bs0 + 8192);
  if (NT > 1) {
    stage_half(Wg, bn,       64, Bs1);
    stage_half(Wg, bn + 128, 64, Bs1 + 8192);
    asm volatile("s_waitcnt vmcnt(4)" ::: "memory");
  } else {
    asm volatile("s_waitcnt vmcnt(0)" ::: "memory");
  }
  __builtin_amdgcn_s_barrier();

  f32x4 acc[8][4] = {};

  for (int t = 0; t < NT; ++t) {
    const char* Ab = (const char*)((t & 1) ? As1 : As0);
    const char* Bb = (const char*)((t & 1) ? Bs1 : Bs0);
    bf16* Asn  = (t & 1) ? As0 : As1;  // A dest for tile t+1 (other buffer)
    bf16* Bsn2 = (t & 1) ? Bs1 : Bs0;  // B dest for tile t+2 (same parity as t)

    bf16x8 bfr[4][2];
#pragma unroll
    for (int ph = 0; ph < 4; ++ph) {
      if (ph == 0) {
#pragma unroll
        for (int j = 0; j < 4; ++j) {
          const int rn = wc * 64 + j * 16 + mfrag;
#pragma unroll
          for (int kh = 0; kh < 2; ++kh)
            bfr[j][kh] = *(const bf16x8*)(Bb + ((rn * 128 + kh * 64 + quad * 16) ^ m7x16));
        }
      }
      bf16x8 afr[2][2];
#pragma unroll
      for (int r = 0; r < 2; ++r) {
        const int ra = wr * 128 + (ph * 2 + r) * 16 + mfrag;
#pragma unroll
        for (int kh = 0; kh < 2; ++kh)
          afr[r][kh] = *(const bf16x8*)(Ab + ((ra * 128 + kh * 64 + quad * 16) ^ m7x16));
      }

      if (ph == 0 && t + 1 < NT) stage_half(Ag, bm,       (t + 1) * 64, Asn);
      if (ph == 1 && t + 1 < NT) stage_half(Ag, bm + 128, (t + 1) * 64, Asn + 8192);
      if (ph == 2 && t + 2 < NT) stage_half(Wg, bn,       (t + 2) * 64, Bsn2);
      if (ph == 3 && t + 2 < NT) stage_half(Wg, bn + 128, (t + 2) * 64, Bsn2 + 8192);

      __builtin_amdgcn_s_barrier();
      asm volatile("s_waitcnt lgkmcnt(0)" ::: "memory");
      __builtin_amdgcn_s_setprio(1);
#pragma unroll
      for (int r = 0; r < 2; ++r)
#pragma unroll
        for (int j = 0; j < 4; ++j)
#pragma unroll
          for (int kh = 0; kh < 2; ++kh)
            acc[ph * 2 + r][j] = __builtin_amdgcn_mfma_f32_16x16x32_bf16(
                afr[r][kh], bfr[j][kh], acc[ph * 2 + r][j], 0, 0, 0);
      __builtin_amdgcn_s_setprio(0);
      if (ph == 3) {
        if (t < NT - 2) asm volatile("s_waitcnt vmcnt(4)" ::: "memory");
        else            asm volatile("s_waitcnt vmcnt(0)" ::: "memory");
      }
      __builtin_amdgcn_s_barrier();
    }
  }

  const int rq = quad * 4;
#pragma unroll
  for (int i = 0; i < 8; ++i)
#pragma unroll
    for (int j = 0; j < 4; ++j)
#pragma unroll
      for (int r = 0; r < 4; ++r) {
        const int row = bm + wr * 128 + i * 16 + rq + r;
        const int col = bn + wc * 64 + j * 16 + mfrag;
        store_out(&C[(size_t)row * N + col], acc[i][j][r]);
      }
}

// ---------------------------------------------------------------------------
// 256x128 variant (same verified schedule, narrower B): 3 stage_half per
// tile. Steady-state drain vmcnt(2). LDS: A 2x32KB + B 2x16KB = 96 KB.
// ---------------------------------------------------------------------------
template <typename OutT, int LD, int KLEN>
__device__ __forceinline__ void gemm256x128_body(
    const bf16* __restrict__ Ag, const bf16* __restrict__ Wg, OutT* __restrict__ C,
    int bm, int bn, int N, bf16* As0, bf16* As1, bf16* Bs0, bf16* Bs1)
{
  constexpr int NT = KLEN / 64;
  const int tid   = threadIdx.x;
  const int lane  = tid & 63;
  const int w     = tid >> 6;
  const int wr    = w >> 2;            // 0..1 : A row-half (128 rows)
  const int wc    = w & 3;             // 0..3 : 32-col slice
  const int mfrag = lane & 15;
  const int quad  = lane >> 4;
  const int m7x16 = (mfrag & 7) << 4;

  auto stage_half = [&](const bf16* __restrict__ G, int grow0, int k0, bf16* dsthalf) {
#pragma unroll
    for (int l = 0; l < 2; ++l) {
      const int o    = l * 8192 + tid * 16;
      const int row  = o >> 7;
      const int slot = ((o >> 4) & 7) ^ (row & 7);
      const bf16* src = G + (size_t)(grow0 + row) * LD + k0 + slot * 8;
      GLOAD_LDS16(src, (char*)dsthalf + l * 8192 + w * 1024);
    }
  };

  // prologue: tile 0 complete + B(1) in flight
  stage_half(Ag, bm,       0, As0);
  stage_half(Ag, bm + 128, 0, As0 + 8192);
  stage_half(Wg, bn, 0, Bs0);
  stage_half(Wg, bn, 64, Bs1);
  asm volatile("s_waitcnt vmcnt(2)" ::: "memory");
  __builtin_amdgcn_s_barrier();

  f32x4 acc[8][2] = {};

  for (int t = 0; t < NT; ++t) {
    const char* Ab = (const char*)((t & 1) ? As1 : As0);
    const char* Bb = (const char*)((t & 1) ? Bs1 : Bs0);
    bf16* Asn  = (t & 1) ? As0 : As1;
    bf16* Bsn2 = (t & 1) ? Bs1 : Bs0;

    bf16x8 bfr[2][2];
#pragma unroll
    for (int ph = 0; ph < 4; ++ph) {
      if (ph == 0) {
#pragma unroll
        for (int j = 0; j < 2; ++j) {
          const int rn = wc * 32 + j * 16 + mfrag;
#pragma unroll
          for (int kh = 0; kh < 2; ++kh)
            bfr[j][kh] = *(const bf16x8*)(Bb + ((rn * 128 + kh * 64 + quad * 16) ^ m7x16));
        }
      }
      bf16x8 afr[2][2];
#pragma unroll
      for (int r = 0; r < 2; ++r) {
        const int ra = wr * 128 + (ph * 2 + r) * 16 + mfrag;
#pragma unroll
        for (int kh = 0; kh < 2; ++kh)
          afr[r][kh] = *(const bf16x8*)(Ab + ((ra * 128 + kh * 64 + quad * 16) ^ m7x16));
      }

      if (ph == 0 && t + 1 < NT) stage_half(Ag, bm,       (t + 1) * 64, Asn);
      if (ph == 1 && t + 1 < NT) stage_half(Ag, bm + 128, (t + 1) * 64, Asn + 8192);
      if (ph == 2 && t + 2 < NT) stage_half(Wg, bn,       (t + 2) * 64, Bsn2);

      __builtin_amdgcn_s_barrier();
      asm volatile("s_waitcnt lgkmcnt(0)" ::: "memory");
      __builtin_amdgcn_s_setprio(1);
#pragma unroll
      for (int r = 0; r < 2; ++r)
#pragma unroll
        for (int j = 0; j < 2; ++j)
#pragma unroll
          for (int kh = 0; kh < 2; ++kh)
            acc[ph * 2 + r][j] = __builtin_amdgcn_mfma_f32_16x16x32_bf16(
                afr[r][kh], bfr[j][kh], acc[ph * 2 + r][j], 0, 0, 0);
      __builtin_amdgcn_s_setprio(0);
      if (ph == 3) {
        if (t < NT - 2) asm volatile("s_waitcnt vmcnt(2)" ::: "memory");
        else            asm volatile("s_waitcnt vmcnt(0)" ::: "memory");
      }
      __builtin_amdgcn_s_barrier();
    }
  }

  const int rq = quad * 4;
#pragma unroll
  for (int i = 0; i < 8; ++i)
#pragma unroll
    for (int j = 0; j < 2; ++j)
#pragma unroll
      for (int r = 0; r < 4; ++r) {
        const int row = bm + wr * 128 + i * 16 + rq + r;
        const int col = bn + wc * 32 + j * 16 + mfrag;
        store_out(&C[(size_t)row * N + col], acc[i][j][r]);
      }
}

// qkv: grid 12x16 = 192 blocks; XCD-chunked swizzle (192 = 8*24, bijective)
__global__ __launch_bounds__(512, 2) void gemm_qkv256(
    const bf16* __restrict__ X,  const bf16* __restrict__ Wq,
    const bf16* __restrict__ Wk, const bf16* __restrict__ Wv,
    bf16* __restrict__ Qo, bf16* __restrict__ Ko, bf16* __restrict__ Vo)
{
  __shared__ alignas(16) bf16 As[2][16384];
  __shared__ alignas(16) bf16 Bs[2][16384];
  const int orig = blockIdx.y * 12 + blockIdx.x;
  const int swz  = (orig & 7) * 24 + (orig >> 3);
  const int bx   = swz % 12;
  const int by   = swz / 12;
  const bf16* W; bf16* C; int N, bn;
  if (bx < 8)       { W = Wq; C = Qo; N = 2048; bn = bx * 256; }
  else if (bx < 10) { W = Wk; C = Ko; N = 512;  bn = (bx - 8) * 256; }
  else              { W = Wv; C = Vo; N = 512;  bn = (bx - 10) * 256; }
  gemm256_body<bf16, 2048, 2048>(X, W, C, by * 256, bn, N,
                                 As[0], As[1], Bs[0], Bs[1]);
}

// out-proj: BM=256 x BN=128 -> grid 16x16 = 256 blocks (full machine);
// XCD-chunked swizzle (256 = 8*32, bijective)
__global__ __launch_bounds__(512, 2) void gemm_out256(
    const bf16* __restrict__ A, const bf16* __restrict__ W, float* __restrict__ C)
{
  __shared__ alignas(16) bf16 As[2][16384];
  __shared__ alignas(16) bf16 Bs[2][8192];
  const int orig = blockIdx.y * 16 + blockIdx.x;
  const int swz  = (orig & 7) * 32 + (orig >> 3);
  const int bx   = swz & 15;
  const int by   = swz >> 4;
  gemm256x128_body<float, 2048, 2048>(A, W, C, by * 256, bx * 128, 2048,
                                      As[0], As[1], Bs[0], Bs[1]);
}

// ---------------------------------------------------------------------------
// post-QKV fixups in one kernel: rope(Q), rope(K), transpose(V)
// ---------------------------------------------------------------------------
__device__ __forceinline__ void rope_row(
    bf16* __restrict__ buf, const float* __restrict__ gain,
    int nh, float scale, int row)
{
  const int j = threadIdx.x & 63;
  const int bt = row / nh;
  const int h  = row - bt * nh;
  const int t  = bt & 2047;  // T = 2048
  bf16* p = buf + (size_t)bt * (nh * 128) + h * 128;

  float x1 = __bfloat162float(p[j]);
  float x2 = __bfloat162float(p[j + 64]);
  float ss = x1 * x1 + x2 * x2;
#pragma unroll
  for (int off = 32; off > 0; off >>= 1) ss += __shfl_xor(ss, off, 64);
  const float rinv = rsqrtf(ss * (1.0f / 128.0f) + 1.1920928955078125e-07f);
  const float g = gain ? gain[h] : 1.0f;
  const float s = rinv * g * scale;

  // base = 10000 * 2^(128/126) (T=2048 > TRAIN=1024); log2(base) = 14.3035853954
  const float inv_freq = exp2f(-(float)j * (14.3035853954f / 64.0f));
  const float fr = (float)t * inv_freq;
  const float cs = cosf(fr), sn = sinf(fr);
  p[j]      = __float2bfloat16(s * (x1 * cs + x2 * sn));
  p[j + 64] = __float2bfloat16(s * (x2 * cs - x1 * sn));
}

__global__ __launch_bounds__(256) void postqkv(
    bf16* __restrict__ qb, bf16* __restrict__ kb,
    const unsigned short* __restrict__ vb, unsigned short* __restrict__ vtb,
    const float* __restrict__ gain)
{
  const int bx = blockIdx.x;
  if (bx < 16384) {
    rope_row(qb, gain, 16, 0.08838834764831845f, bx * 4 + (threadIdx.x >> 6));
  } else if (bx < 20480) {
    rope_row(kb, nullptr, 4, 1.0f, (bx - 16384) * 4 + (threadIdx.x >> 6));
  } else {
    const int idx = (bx - 20480) * 256 + threadIdx.x;  // 256K threads
    const int t  = idx & 4095;
    const int dc = idx >> 12;                          // [0,64)
    u16x8 v = *(const u16x8*)(vb + (size_t)t * 512 + dc * 8);
#pragma unroll
    for (int j = 0; j < 8; ++j)
      vtb[(size_t)(dc * 8 + j) * 4096 + t] = v[j];
  }
}

// ---------------------------------------------------------------------------
// MFMA flash attention v5: R5-verified v3 structure with 32 q-rows per wave
// (two 16-row groups A/B sharing every K/V fragment read). Causal, GQA.
// Fixed softmax max M=14 (S <= 11.31 by Cauchy-Schwarz after rmsnorm).
// Per wave per 64-key tile: 16 kf + 16 vf + 4 pf ds_read_b128 + 32 P-writes
// feed 64 MFMA (LDS:MFMA 2:1 vs v3's 3.25:1). Block = 4 waves = 128 q-rows;
// q-tile pair (15-p, p) -> uniform 34 kt-tiles; grid 8p x 32bh = 256 blocks
// (1/CU). K/V double-buffered + prefetched 1 tile ahead; ONE barrier/tile.
// LDS 80 KB. All address formulas are the R5-verified ones.
// ---------------------------------------------------------------------------
__global__ __launch_bounds__(256) void flash_attn(
    const bf16* __restrict__ Q, const bf16* __restrict__ Kg,
    const bf16* __restrict__ Vtg, bf16* __restrict__ Y)
{
  __shared__ bf16 Ks[2][64 * 128];   // [key][d], XOR-swizzled 16B chunks
  __shared__ bf16 Vs[2][128 * 64];   // [d][key], swizzled
  __shared__ bf16 Ps[4][2][16 * 64]; // per-wave-per-group P [q][key], swizzled

  const int tid = threadIdx.x, lane = tid & 63, w = tid >> 6;
  const int p = blockIdx.x & 7, bh = blockIdx.x >> 3;
  const int h = bh & 15, b = bh >> 4, kvh = h >> 2;
  const int mfrag = lane & 15, quad = lane >> 4;
  const int m7 = mfrag & 7;

  auto stage_k = [&](int kt, int s) {
#pragma unroll
    for (int g = 0; g < 4; ++g) {
      const int o = g * 4096 + w * 1024 + lane * 16;  // byte offset, 256 B rows
      const int r = o >> 8, c = (o >> 4) & 15;
      const int cs = (c & 8) | ((c ^ (r & 7)) & 7);
      const bf16* src = Kg + ((size_t)(b * 2048 + kt * 64 + r)) * 512 + kvh * 128 + cs * 8;
      GLOAD_LDS16(src, (char*)&Ks[s][0] + g * 4096 + w * 1024);
    }
  };
  auto stage_v = [&](int kt, int s) {
#pragma unroll
    for (int g = 0; g < 4; ++g) {
      const int o = g * 4096 + w * 1024 + lane * 16;  // byte offset, 128 B rows
      const int r = o >> 7, c = (o >> 4) & 7;
      const int cs = (c ^ (r & 7)) & 7;
      const bf16* src = Vtg + ((size_t)(kvh * 128 + r)) * 4096 + b * 2048 + kt * 64 + cs * 8;
      GLOAD_LDS16(src, (char*)&Vs[s][0] + g * 4096 + w * 1024);
    }
  };

  stage_k(0, 0);
  stage_v(0, 0);
  int sb = 0;
  bf16* pswA = &Ps[w][0][0];
  bf16* pswB = &Ps[w][1][0];

  for (int phase = 0; phase < 2; ++phase) {
    const int qt = phase ? p : 15 - p;      // 128-row q-tile index
    const int nkt = 2 * qt + 2;             // kt tiles: 0 .. 2qt+1

    // Q fragments for both 16-row groups (rows qt*128 + w*32 + g*16 + mfrag)
    const bf16* qrowA = Q + ((size_t)(b * 2048 + qt * 128 + w * 32 + mfrag)) * 2048 + h * 128;
    const bf16* qrowB = qrowA + 16 * 2048;
    bf16x8 qfA[4], qfB[4];
#pragma unroll
    for (int c = 0; c < 4; ++c) {
      qfA[c] = *(const bf16x8*)(qrowA + c * 32 + quad * 8);
      qfB[c] = *(const bf16x8*)(qrowB + c * 32 + quad * 8);
    }

    f32x4 oaccA[8] = {}, oaccB[8] = {};
    float lA[4] = {0.f, 0.f, 0.f, 0.f}, lB[4] = {0.f, 0.f, 0.f, 0.f};
    const int qbA = qt * 128 + w * 32 + quad * 4;
    const int qbB = qbA + 16;

    for (int kt = 0; kt < nkt; ++kt) {
      __syncthreads();  // prefetch into [sb] drained; [sb^1] free for overwrite
      const bool last = (phase == 1) && (kt == nkt - 1);
      if (!last) {
        const int nk = (kt < nkt - 1) ? kt + 1 : 0;
        stage_k(nk, sb ^ 1);
        stage_v(nk, sb ^ 1);
      }

      // ---- S = Q K^T for both groups; each kf feeds 2 MFMAs
      f32x4 scA[4] = {}, scB[4] = {};
      __builtin_amdgcn_s_setprio(1);
#pragma unroll
      for (int kc = 0; kc < 4; ++kc) {
        const bf16* krow = &Ks[sb][0] + (kc * 16 + mfrag) * 128;
#pragma unroll
        for (int c = 0; c < 4; ++c) {
          const int G = 4 * c + quad;
          const int cs = (G & 8) | ((G ^ m7) & 7);
          bf16x8 kf = *(const bf16x8*)(krow + cs * 8);
          scA[kc] = __builtin_amdgcn_mfma_f32_16x16x32_bf16(qfA[c], kf, scA[kc], 0, 0, 0);
          scB[kc] = __builtin_amdgcn_mfma_f32_16x16x32_bf16(qfB[c], kf, scB[kc], 0, 0, 0);
        }
      }
      __builtin_amdgcn_s_setprio(0);

      // ---- causal mask (last two kt tiles overlap the diagonal)
      if (kt >= 2 * qt) {
        const int kcol0 = kt * 64 + mfrag;
#pragma unroll
        for (int kc = 0; kc < 4; ++kc)
#pragma unroll
          for (int r = 0; r < 4; ++r) {
            if (kcol0 + kc * 16 > qbA + r) scA[kc][r] = -1e30f;
            if (kcol0 + kc * 16 > qbB + r) scB[kc][r] = -1e30f;
          }
      }

      // ---- P = exp(S - 14); per-lane l accumulation (no cross-lane ops)
#pragma unroll
      for (int kc = 0; kc < 4; ++kc)
#pragma unroll
        for (int r = 0; r < 4; ++r) {
          const int q = quad * 4 + r;
          const int slot = ((2 * kc + (mfrag >> 3)) ^ (q & 7)) & 7;
          const float pvA = __expf(scA[kc][r] - 14.0f);
          lA[r] += pvA;
          pswA[q * 64 + slot * 8 + m7] = __float2bfloat16(pvA);
          const float pvB = __expf(scB[kc][r] - 14.0f);
          lB[r] += pvB;
          pswB[q * 64 + slot * 8 + m7] = __float2bfloat16(pvB);
        }

      // ---- O += P V; each vf feeds 2 MFMAs
      __builtin_amdgcn_s_setprio(1);
#pragma unroll
      for (int kh = 0; kh < 2; ++kh) {
        const int Gp = 4 * kh + quad;
        const int sl = (Gp ^ m7) & 7;
        bf16x8 pfA = *(const bf16x8*)(pswA + mfrag * 64 + sl * 8);
        bf16x8 pfB = *(const bf16x8*)(pswB + mfrag * 64 + sl * 8);
#pragma unroll
        for (int dc = 0; dc < 8; ++dc) {
          bf16x8 vf = *(const bf16x8*)(&Vs[sb][0] + (dc * 16 + mfrag) * 64 + sl * 8);
          oaccA[dc] = __builtin_amdgcn_mfma_f32_16x16x32_bf16(pfA, vf, oaccA[dc], 0, 0, 0);
          oaccB[dc] = __builtin_amdgcn_mfma_f32_16x16x32_bf16(pfB, vf, oaccB[dc], 0, 0, 0);
        }
      }
      __builtin_amdgcn_s_setprio(0);
      sb ^= 1;
    }

    // ---- epilogue: reduce l across the 16 lanes holding each row, store
#pragma unroll
    for (int r = 0; r < 4; ++r) {
      float la = lA[r];
      la += __shfl_xor(la, 1, 64);
      la += __shfl_xor(la, 2, 64);
      la += __shfl_xor(la, 4, 64);
      la += __shfl_xor(la, 8, 64);
      const float linvA = 1.0f / la;
      const size_t rowA = (size_t)(b * 2048 + qbA + r);
#pragma unroll
      for (int dc = 0; dc < 8; ++dc)
        Y[rowA * 2048 + h * 128 + dc * 16 + mfrag] = __float2bfloat16(oaccA[dc][r] * linvA);

      float lb = lB[r];
      lb += __shfl_xor(lb, 1, 64);
      lb += __shfl_xor(lb, 2, 64);
      lb += __shfl_xor(lb, 4, 64);
      lb += __shfl_xor(lb, 8, 64);
      const float linvB = 1.0f / lb;
      const size_t rowB = (size_t)(b * 2048 + qbB + r);
#pragma unroll
      for (int dc = 0; dc < 8; ++dc)
        Y[rowB * 2048 + h * 128 + dc * 16 + mfrag] = __float2bfloat16(oaccB[dc][r] * linvB);
    }
  }
}

// ---------------------------------------------------------------------------
extern "C" void kernel_launch(void* const* d_in, const int* in_sizes, int n_in,
                              void* d_out, int out_size, void* d_ws, size_t ws_size,
                              hipStream_t stream)
{
  const float* x      = (const float*)d_in[0];
  const float* q_w    = (const float*)d_in[1];
  const float* k_w    = (const float*)d_in[2];
  const float* v_w    = (const float*)d_in[3];
  const float* o_w    = (const float*)d_in[4];
  const float* q_gain = (const float*)d_in[5];
  float* out = (float*)d_out;

  // workspace (bf16): xb aliases yb (x dead after QKV GEMM); vtb reuses qwb
  // region (q_w copy dead after QKV GEMM).
  char* ws = (char*)d_ws;
  bf16* xb  = (bf16*)(ws);                   // 4096x2048 = 16 MB
  bf16* yb  = (bf16*)(ws);                   // alias of xb
  bf16* qwb = (bf16*)(ws + (16u << 20));     // 2048x2048 = 8 MB
  bf16* vtb = (bf16*)(ws + (16u << 20));     // 512x4096  = 4 MB (after qwb dead)
  bf16* owb = (bf16*)(ws + (24u << 20));     // 2048x2048 = 8 MB
  bf16* kwb = (bf16*)(ws + (32u << 20));     // 512x2048  = 2 MB
  bf16* vwb = (bf16*)(ws + (34u << 20));     // 512x2048  = 2 MB
  bf16* qb  = (bf16*)(ws + (36u << 20));     // 4096x2048 = 16 MB
  bf16* kb  = (bf16*)(ws + (52u << 20));     // 4096x512  = 4 MB
  bf16* vb  = (bf16*)(ws + (56u << 20));     // 4096x512  = 4 MB  (total 60 MB)

  cvt_all<<<dim3(18432), dim3(256), 0, stream>>>(
      (const float4*)x, (const float4*)q_w, (const float4*)k_w,
      (const float4*)v_w, (const float4*)o_w,
      (ushort4*)xb, (ushort4*)qwb, (ushort4*)kwb, (ushort4*)vwb, (ushort4*)owb);

  gemm_qkv256<<<dim3(12, 16), dim3(512), 0, stream>>>(xb, qwb, kwb, vwb, qb, kb, vb);

  postqkv<<<dim3(21504), dim3(256), 0, stream>>>(
      qb, kb, (const unsigned short*)vb, (unsigned short*)vtb, q_gain);

  flash_attn<<<dim3(256), dim3(256), 0, stream>>>(qb, kb, vtb, yb);

  gemm_out256<<<dim3(16, 16), dim3(512), 0, stream>>>(yb, owb, out);
}